// Round 21
// baseline (208.181 us; speedup 1.0000x reference)
//
#include <hip/hip_runtime.h>
#include <hip/hip_bf16.h>

// Interpolate1D — ROUND 21: ABLATION ROUND (m164/m165 method).
// 20 rounds of hypothesis-driven probes plateaued at 59.5us (r18/r20) vs a ~35us
// traffic floor, with no pipe saturated and occupancy/regalloc immovable. Before
// declaring, measure where the time actually goes: 4 co-compiled variants, all
// launched every call (headline dur = sum; per-dispatch rocprof rows give the split).
//   MODE 1: memory-structure only (x loads + nt passthrough + trivial z; loads kept
//           live via shuffle+store — rule #17 no-DCE).
//   MODE 2: full compute, passthrough stores REMOVED (write-stream interference).
//   MODE 3: full, exp2 -> identity (TRANS pipe cost).
//   MODE 0: production r20 body, launched LAST -> d_out fully correct.
// Structure (LDS size, launch config, loop shape) identical across modes so dur
// deltas attribute to the removed work, not occupancy shifts.

#define NB 524288
#define NWT (NB / 16)   // 32768 wave-tiles of 16 rows

typedef __attribute__((ext_vector_type(4))) float f32x4;
typedef __attribute__((ext_vector_type(4))) unsigned int u32x4;
typedef __attribute__((ext_vector_type(8))) __bf16 bf16x8;

#define LOG2E 1.4426950408889634f

static __device__ __forceinline__ unsigned short f2b(float f) {
    unsigned u = __builtin_bit_cast(unsigned, f);
    u += 0x7fffu + ((u >> 16) & 1u);
    return (unsigned short)(u >> 16);
}
static __device__ __forceinline__ unsigned pk2t(float a, float b) {
    return (__builtin_bit_cast(unsigned, a) >> 16) | (__builtin_bit_cast(unsigned, b) & 0xffff0000u);
}

template <int MODE>   // 0=full  1=mem-only  2=no-passthrough  3=no-exp
__global__ __launch_bounds__(512, 4) void interp1d_kernel(
    const float* __restrict__ y, const float* __restrict__ x,
    const float* __restrict__ W, const float* __restrict__ bias,
    const float* __restrict__ logdet, const float* __restrict__ bp,
    float* __restrict__ out)
{
    __shared__ unsigned short sW[2 * 16 * 64 * 8];   // kept in ALL modes (same occupancy)
    __shared__ float sBP[256];
    __shared__ float sBias[256];

    const int t = threadIdx.x;

    if (t < 256) {
        sBP[t]   = bp[t];
        sBias[t] = bias[t] * LOG2E;
    }
    if (MODE != 1) {   // W pack not needed for the mem-only probe
        const int col = t & 255;
        const int k0  = (t >> 8) << 5;
        const int lane16lo = col & 15;
        const int n = col >> 4;
        for (int kk = 0; kk < 32; ++kk) {
            int k = k0 + kk;
            float wv = W[k * 256 + col] * LOG2E;
            int lane16 = ((k >> 3) & 3) * 16 + lane16lo;
            int kb = k >> 5, i = k & 7;
            sW[((kb * 16 + n) * 64 + lane16) * 8 + i] = f2b(wv);
        }
    }
    __syncthreads();

    const int lane = t & 63;
    const int colb = lane & 15;
    const int kH   = lane >> 4;
    const int nw   = gridDim.x << 3;

    int wt = (blockIdx.x << 3) | (t >> 6);

    f32x4 v0 = {}, v1 = {}, v2 = {}, v3 = {};
    float yv = 0.f, ldv = 0.f;
    if (wt < NWT) {
        const float* xr = x + (size_t)((wt << 4) + colb) * 64 + (kH << 3);
        v0 = *reinterpret_cast<const f32x4*>(xr);
        v1 = *reinterpret_cast<const f32x4*>(xr + 4);
        v2 = *reinterpret_cast<const f32x4*>(xr + 32);
        v3 = *reinterpret_cast<const f32x4*>(xr + 36);
        yv  = y[(wt << 4) + colb];
        ldv = logdet[(wt << 4) + colb];
    }

    for (; wt < NWT; wt += nw) {
        const int m0 = wt << 4;
        const int wtn = wt + nw;

        f32x4 n0 = {}, n1 = {}, n2 = {}, n3 = {};
        float yn = 0.f, ldn = 0.f;
        if (wtn < NWT) {
            const float* xr = x + (size_t)((wtn << 4) + colb) * 64 + (kH << 3);
            n0 = *reinterpret_cast<const f32x4*>(xr);
            n1 = *reinterpret_cast<const f32x4*>(xr + 4);
            n2 = *reinterpret_cast<const f32x4*>(xr + 32);
            n3 = *reinterpret_cast<const f32x4*>(xr + 36);
            yn  = y[(wtn << 4) + colb];
            ldn = logdet[(wtn << 4) + colb];
        }

        asm volatile("" ::: "memory");

        if (MODE != 2) {   // nt passthrough stores
            float* xo = out + NB + (size_t)(m0 + colb) * 64 + (kH << 3);
            __builtin_nontemporal_store(v0, reinterpret_cast<f32x4*>(xo));
            __builtin_nontemporal_store(v1, reinterpret_cast<f32x4*>(xo + 4));
            __builtin_nontemporal_store(v2, reinterpret_cast<f32x4*>(xo + 32));
            __builtin_nontemporal_store(v3, reinterpret_cast<f32x4*>(xo + 36));
        }

        if (MODE == 1) {
            // keep every load live: fold into a cross-lane sum that reaches a store
            float sum = v0[0] + v1[1] + v2[2] + v3[3] + yv;
            sum += __shfl_xor(sum, 16, 64);
            sum += __shfl_xor(sum, 32, 64);
            if (kH == 0) {
                __builtin_nontemporal_store(sum, out + m0 + colb);
                __builtin_nontemporal_store(ldv, out + (size_t)NB * 65 + m0 + colb);
            }
        } else {
            u32x4 pa, pb;
            pa[0] = pk2t(v0[0], v0[1]); pa[1] = pk2t(v0[2], v0[3]);
            pa[2] = pk2t(v1[0], v1[1]); pa[3] = pk2t(v1[2], v1[3]);
            pb[0] = pk2t(v2[0], v2[1]); pb[1] = pk2t(v2[2], v2[3]);
            pb[2] = pk2t(v3[0], v3[1]); pb[3] = pk2t(v3[2], v3[3]);
            bf16x8 a0 = __builtin_bit_cast(bf16x8, pa);
            bf16x8 a1 = __builtin_bit_cast(bf16x8, pb);

            int s = (int)floorf(yv * 255.0f);
            s = min(254, max(0, s));
            s += (sBP[s + 1] <= yv) ? 1 : 0;
            s = min(s, 254);
            s -= (sBP[s] > yv) ? 1 : 0;
            s = max(s, 0);

            const int sb  = s >> 4,  so  = s & 15;
            const int sb1 = (s + 1) >> 4, so1 = (s + 1) & 15;
            float m[4], pm[4];
            #pragma unroll
            for (int j = 0; j < 4; ++j) {
                m[j]  = ((kH << 2) + j <= so)  ? 1.f : 0.f;
                pm[j] = ((kH << 2) + j == so1) ? 1.f : 0.f;
            }

            float denom = 0.f, f0s = 0.f, p1 = 0.f;
            #pragma unroll
            for (int n = 0; n < 16; ++n) {
                bf16x8 w0 = *reinterpret_cast<const bf16x8*>(&sW[(n * 64 + lane) * 8]);
                bf16x8 w1 = *reinterpret_cast<const bf16x8*>(&sW[((16 + n) * 64 + lane) * 8]);
                f32x4 c = *reinterpret_cast<const f32x4*>(&sBias[(n << 4) + (kH << 2)]);
                c = __builtin_amdgcn_mfma_f32_16x16x32_bf16(w0, a0, c, 0, 0, 0);
                c = __builtin_amdgcn_mfma_f32_16x16x32_bf16(w1, a1, c, 0, 0, 0);
                float e0 = (MODE == 3) ? c[0] : __builtin_amdgcn_exp2f(c[0]);
                float e1 = (MODE == 3) ? c[1] : __builtin_amdgcn_exp2f(c[1]);
                float e2 = (MODE == 3) ? c[2] : __builtin_amdgcn_exp2f(c[2]);
                float e3 = (MODE == 3) ? c[3] : __builtin_amdgcn_exp2f(c[3]);
                float bs = (e0 + e1) + (e2 + e3);
                denom += bs;
                float t0 = fmaf(e3, m[3], fmaf(e2, m[2], fmaf(e1, m[1], e0 * m[0])));
                float tp = fmaf(e3, pm[3], fmaf(e2, pm[2], fmaf(e1, pm[1], e0 * pm[0])));
                f0s += (n < sb) ? bs : ((n == sb) ? t0 : 0.f);
                p1  += (n == sb1) ? tp : 0.f;
            }

            denom += __shfl_xor(denom, 16, 64);
            f0s   += __shfl_xor(f0s,   16, 64);
            p1    += __shfl_xor(p1,    16, 64);
            denom += __shfl_xor(denom, 32, 64);
            f0s   += __shfl_xor(f0s,   32, 64);
            p1    += __shfl_xor(p1,    32, 64);

            if (kH == 0) {
                float x0 = sBP[s], x1 = sBP[s + 1];
                float inv = 1.0f / denom;
                float f0 = f0s * inv;
                float slope = (p1 * inv) / (x1 - x0);
                __builtin_nontemporal_store(fmaf(slope, yv - x0, f0), out + m0 + colb);
                __builtin_nontemporal_store(ldv + __logf(fabsf(slope)),
                                            out + (size_t)NB * 65 + m0 + colb);
            }
        }

        if (wtn < NWT) {
            v0 = n0; v1 = n1; v2 = n2; v3 = n3;
            yv = yn; ldv = ldn;
        }
    }
}

extern "C" void kernel_launch(void* const* d_in, const int* in_sizes, int n_in,
                              void* d_out, int out_size, void* d_ws, size_t ws_size,
                              hipStream_t stream) {
    (void)in_sizes; (void)n_in; (void)out_size; (void)d_ws; (void)ws_size;
    const float* y      = (const float*)d_in[0];
    const float* x      = (const float*)d_in[1];
    const float* W      = (const float*)d_in[2];
    const float* b      = (const float*)d_in[3];
    const float* logdet = (const float*)d_in[4];
    const float* bp     = (const float*)d_in[5];
    float* out = (float*)d_out;

    // Diagnostics first (their partial/garbage d_out writes are overwritten by MODE 0).
    interp1d_kernel<1><<<dim3(1024), dim3(512), 0, stream>>>(y, x, W, b, logdet, bp, out);
    interp1d_kernel<2><<<dim3(1024), dim3(512), 0, stream>>>(y, x, W, b, logdet, bp, out);
    interp1d_kernel<3><<<dim3(1024), dim3(512), 0, stream>>>(y, x, W, b, logdet, bp, out);
    // Production (r20 body) LAST: writes every output element -> d_out correct.
    interp1d_kernel<0><<<dim3(1024), dim3(512), 0, stream>>>(y, x, W, b, logdet, bp, out);
}

// Round 22
// 56.037 us; speedup vs baseline: 3.7150x; 3.7150x over previous
//
#include <hip/hip_runtime.h>
#include <hip/hip_bf16.h>

// Interpolate1D: z = interp(cumsum(softmax(x@W + b)), y); outputs (z[B], x[B,64], logdet[B]+log|slope|)
// B=524288, D=64, R=256.
//
// Round-22: LANE-LINEAR global path + per-wave LDS transpose.
//   r21 ablation: memory-structure-only (MODE1) = 85-90us profiled vs full 93 ->
//   ~95% of runtime is the x-copy path at 2.7 TB/s (ideal copy: 6.3). Cause: all
//   loads/stores were 16B/lane at 256B stride (scattered per instruction) and nt
//   stores of partial lines amplified WRITE 134->155-163MB.
//   Fix: loads/stores lane-linear (xg[j*64+lane]: 1KB contiguous per wave instr,
//   full-line nt writes); fragments built by staging the tile as bf16 in a
//   PER-WAVE private LDS slab (no barrier; 4x 8B ds_write + 2x ds_read_b128;
//   row stride 144B -> 2-way bank alias = free). LDS 52KB -> 3 blocks/CU.
// Kept from r20 (best 59.5us): fused n-loop, swapped MFMA operands, register
// prefetch, LICM fence, log2e pre-scale + exp2, float-mask prefix sums,
// branchless searchsorted, truncating bf16 pack, nt on all output streams.

#define NB 524288
#define NWT (NB / 16)   // 32768 wave-tiles of 16 rows

typedef __attribute__((ext_vector_type(4))) float f32x4;
typedef __attribute__((ext_vector_type(8))) __bf16 bf16x8;

#define LOG2E 1.4426950408889634f

static __device__ __forceinline__ unsigned short f2b(float f) {
    unsigned u = __builtin_bit_cast(unsigned, f);
    u += 0x7fffu + ((u >> 16) & 1u);          // RNE (W pack only; one-time)
    return (unsigned short)(u >> 16);
}
static __device__ __forceinline__ unsigned pk2t(float a, float b) {
    // truncating bf16x2 pack: hi16(a) | hi16(b)
    return (__builtin_bit_cast(unsigned, a) >> 16) | (__builtin_bit_cast(unsigned, b) & 0xffff0000u);
}

__global__ __launch_bounds__(512, 2) void interp1d_kernel(
    const float* __restrict__ y, const float* __restrict__ x,
    const float* __restrict__ W, const float* __restrict__ bias,
    const float* __restrict__ logdet, const float* __restrict__ bp,
    float* __restrict__ out)
{
    __shared__ unsigned short sW[2 * 16 * 64 * 8];   // 32KB, [kb][n][lane][i] frag layout
    __shared__ unsigned short sX[8 * 16 * 72];       // 18KB: per-wave tile slab, 144B/row
    __shared__ float sBP[256];
    __shared__ float sBias[256];                     // pre-scaled by log2e

    const int t = threadIdx.x;

    // --- once per block: bp, bias*log2e, W*log2e packed into MFMA fragment layout ---
    if (t < 256) {
        sBP[t]   = bp[t];
        sBias[t] = bias[t] * LOG2E;
    }
    {
        const int col = t & 255;
        const int k0  = (t >> 8) << 5;
        const int lane16lo = col & 15;
        const int n = col >> 4;
        for (int kk = 0; kk < 32; ++kk) {
            int k = k0 + kk;
            float wv = W[k * 256 + col] * LOG2E;      // coalesced within each 256-thread half
            int lane16 = ((k >> 3) & 3) * 16 + lane16lo;
            int kb = k >> 5, i = k & 7;
            sW[((kb * 16 + n) * 64 + lane16) * 8 + i] = f2b(wv);
        }
    }
    __syncthreads();

    const int lane = t & 63;
    const int colb = lane & 15;     // this lane's x-row within the tile (C column)
    const int kH   = lane >> 4;     // 0..3: k-half for frags; C row group (cols kH*4+j)
    unsigned short* myX = &sX[(t >> 6) * (16 * 72)];   // this wave's private slab
    const int nw   = gridDim.x << 3;                   // 8 waves per block

    int wt = (blockIdx.x << 3) | (t >> 6);

    // --- preload first tile: LANE-LINEAR (1KB contiguous per wave instruction) ---
    f32x4 v0 = {}, v1 = {}, v2 = {}, v3 = {};
    float yv = 0.f, ldv = 0.f;
    if (wt < NWT) {
        const f32x4* xg = reinterpret_cast<const f32x4*>(x) + (size_t)wt * 256;
        v0 = xg[lane]; v1 = xg[64 + lane]; v2 = xg[128 + lane]; v3 = xg[192 + lane];
        yv  = y[(wt << 4) + colb];
        ldv = logdet[(wt << 4) + colb];
    }

    for (; wt < NWT; wt += nw) {
        const int m0 = wt << 4;
        const int wtn = wt + nw;

        // --- prefetch next tile, lane-linear ---
        f32x4 n0 = {}, n1 = {}, n2 = {}, n3 = {};
        float yn = 0.f, ldn = 0.f;
        if (wtn < NWT) {
            const f32x4* xg = reinterpret_cast<const f32x4*>(x) + (size_t)wtn * 256;
            n0 = xg[lane]; n1 = xg[64 + lane]; n2 = xg[128 + lane]; n3 = xg[192 + lane];
            yn  = y[(wtn << 4) + colb];
            ldn = logdet[(wtn << 4) + colb];
        }

        // compiler fence: keep sW ds_reads inside the tile loop (r3 LICM lesson)
        asm volatile("" ::: "memory");

        // --- nt passthrough: same lane-linear registers -> full-line writes ---
        f32x4* xo = reinterpret_cast<f32x4*>(out + NB) + (size_t)wt * 256;
        __builtin_nontemporal_store(v0, xo + lane);
        __builtin_nontemporal_store(v1, xo + 64 + lane);
        __builtin_nontemporal_store(v2, xo + 128 + lane);
        __builtin_nontemporal_store(v3, xo + 192 + lane);

        // --- stage tile to LDS as bf16 (chunk c = j*64+lane -> row c>>4, pos c&15) ---
        {
            uint2 w; int c, row, pos;
            c = lane;        row = c >> 4; pos = c & 15;
            w.x = pk2t(v0[0], v0[1]); w.y = pk2t(v0[2], v0[3]);
            *reinterpret_cast<uint2*>(&myX[row * 72 + pos * 4]) = w;
            c = 64 + lane;   row = c >> 4; pos = c & 15;
            w.x = pk2t(v1[0], v1[1]); w.y = pk2t(v1[2], v1[3]);
            *reinterpret_cast<uint2*>(&myX[row * 72 + pos * 4]) = w;
            c = 128 + lane;  row = c >> 4; pos = c & 15;
            w.x = pk2t(v2[0], v2[1]); w.y = pk2t(v2[2], v2[3]);
            *reinterpret_cast<uint2*>(&myX[row * 72 + pos * 4]) = w;
            c = 192 + lane;  row = c >> 4; pos = c & 15;
            w.x = pk2t(v3[0], v3[1]); w.y = pk2t(v3[2], v3[3]);
            *reinterpret_cast<uint2*>(&myX[row * 72 + pos * 4]) = w;
        }

        // --- read A-frags: 2x ds_read_b128, same-wave (no barrier; compiler lgkmcnt) ---
        bf16x8 a0 = *reinterpret_cast<const bf16x8*>(&myX[colb * 72 + (kH << 3)]);
        bf16x8 a1 = *reinterpret_cast<const bf16x8*>(&myX[colb * 72 + 32 + (kH << 3)]);

        // --- searchsorted (branchless: bp ~ linspace so guess is off by <= 1) ---
        int s = (int)floorf(yv * 255.0f);
        s = min(254, max(0, s));
        s += (sBP[s + 1] <= yv) ? 1 : 0;   // bp[255]=1.0 > yv, can't reach 255
        s = min(s, 254);
        s -= (sBP[s] > yv) ? 1 : 0;
        s = max(s, 0);

        // --- per-lane float masks for the partial blocks ---
        const int sb  = s >> 4,  so  = s & 15;            // block/offset of s
        const int sb1 = (s + 1) >> 4, so1 = (s + 1) & 15; // block/offset of s+1
        float m[4], pm[4];
        #pragma unroll
        for (int j = 0; j < 4; ++j) {
            m[j]  = ((kH << 2) + j <= so)  ? 1.f : 0.f;
            pm[j] = ((kH << 2) + j == so1) ? 1.f : 0.f;
        }

        // --- FUSED n-loop: MFMA (transient c) -> exp2 -> masked sums ---
        float denom = 0.f, f0s = 0.f, p1 = 0.f;
        #pragma unroll
        for (int n = 0; n < 16; ++n) {
            bf16x8 w0 = *reinterpret_cast<const bf16x8*>(&sW[(n * 64 + lane) * 8]);
            bf16x8 w1 = *reinterpret_cast<const bf16x8*>(&sW[((16 + n) * 64 + lane) * 8]);
            f32x4 c = *reinterpret_cast<const f32x4*>(&sBias[(n << 4) + (kH << 2)]);
            c = __builtin_amdgcn_mfma_f32_16x16x32_bf16(w0, a0, c, 0, 0, 0);
            c = __builtin_amdgcn_mfma_f32_16x16x32_bf16(w1, a1, c, 0, 0, 0);
            float e0 = __builtin_amdgcn_exp2f(c[0]);
            float e1 = __builtin_amdgcn_exp2f(c[1]);
            float e2 = __builtin_amdgcn_exp2f(c[2]);
            float e3 = __builtin_amdgcn_exp2f(c[3]);
            float bs = (e0 + e1) + (e2 + e3);
            denom += bs;
            float t0 = fmaf(e3, m[3], fmaf(e2, m[2], fmaf(e1, m[1], e0 * m[0])));
            float tp = fmaf(e3, pm[3], fmaf(e2, pm[2], fmaf(e1, pm[1], e0 * pm[0])));
            f0s += (n < sb) ? bs : ((n == sb) ? t0 : 0.f);
            p1  += (n == sb1) ? tp : 0.f;
        }

        // --- reduce over the 4 kH lanes sharing this x-row ---
        denom += __shfl_xor(denom, 16, 64);
        f0s   += __shfl_xor(f0s,   16, 64);
        p1    += __shfl_xor(p1,    16, 64);
        denom += __shfl_xor(denom, 32, 64);
        f0s   += __shfl_xor(f0s,   32, 64);
        p1    += __shfl_xor(p1,    32, 64);

        if (kH == 0) {   // lanes 0..15 store rows m0..m0+15: contiguous 64B -> nt safe
            float x0 = sBP[s], x1 = sBP[s + 1];
            float inv = 1.0f / denom;
            float f0 = f0s * inv;
            float slope = (p1 * inv) / (x1 - x0);
            __builtin_nontemporal_store(fmaf(slope, yv - x0, f0), out + m0 + colb);
            __builtin_nontemporal_store(ldv + __logf(fabsf(slope)),
                                        out + (size_t)NB * 65 + m0 + colb);
        }

        // --- rotate prefetched tile in ---
        if (wtn < NWT) {
            v0 = n0; v1 = n1; v2 = n2; v3 = n3;
            yv = yn; ldv = ldn;
        }
    }
}

extern "C" void kernel_launch(void* const* d_in, const int* in_sizes, int n_in,
                              void* d_out, int out_size, void* d_ws, size_t ws_size,
                              hipStream_t stream) {
    (void)in_sizes; (void)n_in; (void)out_size; (void)d_ws; (void)ws_size;
    const float* y      = (const float*)d_in[0];
    const float* x      = (const float*)d_in[1];
    const float* W      = (const float*)d_in[2];
    const float* b      = (const float*)d_in[3];
    const float* logdet = (const float*)d_in[4];
    const float* bp     = (const float*)d_in[5];
    float* out = (float*)d_out;
    // 512-thr blocks, LDS 52KB -> 3 blocks/CU resident; 1024 blocks (queued backfill),
    // 4 tiles/wave.
    interp1d_kernel<<<dim3(1024), dim3(512), 0, stream>>>(y, x, W, b, logdet, bp, out);
}

// Round 23
// 55.302 us; speedup vs baseline: 3.7645x; 1.0133x over previous
//
#include <hip/hip_runtime.h>
#include <hip/hip_bf16.h>

// Interpolate1D: z = interp(cumsum(softmax(x@W + b)), y); outputs (z[B], x[B,64], logdet[B]+log|slope|)
// B=524288, D=64, R=256.
//
// Round-23 = round-22 (best: 56.0us, lane-linear mem path CONFIRMED: WRITE 155->136MB)
// + DEPTH-2 PREFETCH via full unroll:
//   Residual after r22 is latency coverage (HBM 3.7/6.3 TB/s, nothing saturated):
//   depth-1 prefetch gives ~600-700cy of compute to cover a ~900cy HBM miss.
//   NWT = 1024 blocks x 8 waves x 4 tiles EXACTLY -> fully unrolled schedule,
//   zero bounds checks: load T0,T1 | issue T2, proc T0 | issue T3, proc T1 |
//   proc T2 | proc T3. Peak live = 3 tile-sets (~57 regs) + compute ~= 100 regs;
//   (512,2) budget so no 64-reg squeeze (r14 measured 72 clean there). Fences
//   between processes stop sW-read CSE across tiles (r13's 128-reg spill trap).
// Kept from r22: lane-linear loads/nt-stores (full lines), per-wave LDS transpose
// slab, fused n-loop, swapped MFMA operands, log2e + exp2, float-mask prefix sums,
// branchless searchsorted, nt z/logdet stores.

#define NB 524288
#define NWT (NB / 16)   // 32768 wave-tiles; == 1024 blocks * 8 waves * 4 tiles exactly

typedef __attribute__((ext_vector_type(4))) float f32x4;
typedef __attribute__((ext_vector_type(8))) __bf16 bf16x8;

#define LOG2E 1.4426950408889634f

static __device__ __forceinline__ unsigned short f2b(float f) {
    unsigned u = __builtin_bit_cast(unsigned, f);
    u += 0x7fffu + ((u >> 16) & 1u);          // RNE (W pack only; one-time)
    return (unsigned short)(u >> 16);
}
static __device__ __forceinline__ unsigned pk2t(float a, float b) {
    // truncating bf16x2 pack: hi16(a) | hi16(b)
    return (__builtin_bit_cast(unsigned, a) >> 16) | (__builtin_bit_cast(unsigned, b) & 0xffff0000u);
}

struct Tile { f32x4 v0, v1, v2, v3; float yv, ldv; };

static __device__ __forceinline__ void loadT(
    Tile& T, int wt, int lane, int colb,
    const float* __restrict__ x, const float* __restrict__ y,
    const float* __restrict__ logdet)
{
    const f32x4* xg = reinterpret_cast<const f32x4*>(x) + (size_t)wt * 256;
    T.v0 = xg[lane]; T.v1 = xg[64 + lane]; T.v2 = xg[128 + lane]; T.v3 = xg[192 + lane];
    T.yv  = y[(wt << 4) + colb];
    T.ldv = logdet[(wt << 4) + colb];
}

static __device__ __forceinline__ void process(
    const Tile& T, int wt, int lane, int colb, int kH,
    unsigned short* myX, const unsigned short* sW,
    const float* sBP, const float* sBias, float* __restrict__ out)
{
    const int m0 = wt << 4;

    // --- nt passthrough: lane-linear registers -> full-line writes ---
    f32x4* xo = reinterpret_cast<f32x4*>(out + NB) + (size_t)wt * 256;
    __builtin_nontemporal_store(T.v0, xo + lane);
    __builtin_nontemporal_store(T.v1, xo + 64 + lane);
    __builtin_nontemporal_store(T.v2, xo + 128 + lane);
    __builtin_nontemporal_store(T.v3, xo + 192 + lane);

    // --- stage tile to LDS as bf16 (chunk c = j*64+lane -> row c>>4, pos c&15) ---
    {
        uint2 w; int c, row, pos;
        c = lane;        row = c >> 4; pos = c & 15;
        w.x = pk2t(T.v0[0], T.v0[1]); w.y = pk2t(T.v0[2], T.v0[3]);
        *reinterpret_cast<uint2*>(&myX[row * 72 + pos * 4]) = w;
        c = 64 + lane;   row = c >> 4; pos = c & 15;
        w.x = pk2t(T.v1[0], T.v1[1]); w.y = pk2t(T.v1[2], T.v1[3]);
        *reinterpret_cast<uint2*>(&myX[row * 72 + pos * 4]) = w;
        c = 128 + lane;  row = c >> 4; pos = c & 15;
        w.x = pk2t(T.v2[0], T.v2[1]); w.y = pk2t(T.v2[2], T.v2[3]);
        *reinterpret_cast<uint2*>(&myX[row * 72 + pos * 4]) = w;
        c = 192 + lane;  row = c >> 4; pos = c & 15;
        w.x = pk2t(T.v3[0], T.v3[1]); w.y = pk2t(T.v3[2], T.v3[3]);
        *reinterpret_cast<uint2*>(&myX[row * 72 + pos * 4]) = w;
    }

    // --- A-frags: 2x ds_read_b128, same-wave (compiler lgkmcnt; no barrier) ---
    bf16x8 a0 = *reinterpret_cast<const bf16x8*>(&myX[colb * 72 + (kH << 3)]);
    bf16x8 a1 = *reinterpret_cast<const bf16x8*>(&myX[colb * 72 + 32 + (kH << 3)]);

    // --- searchsorted (branchless: bp ~ linspace, guess off by <= 1) ---
    float yv = T.yv;
    int s = (int)floorf(yv * 255.0f);
    s = min(254, max(0, s));
    s += (sBP[s + 1] <= yv) ? 1 : 0;
    s = min(s, 254);
    s -= (sBP[s] > yv) ? 1 : 0;
    s = max(s, 0);

    const int sb  = s >> 4,  so  = s & 15;
    const int sb1 = (s + 1) >> 4, so1 = (s + 1) & 15;
    float m[4], pm[4];
    #pragma unroll
    for (int j = 0; j < 4; ++j) {
        m[j]  = ((kH << 2) + j <= so)  ? 1.f : 0.f;
        pm[j] = ((kH << 2) + j == so1) ? 1.f : 0.f;
    }

    // --- FUSED n-loop: MFMA (transient c) -> exp2 -> masked sums ---
    float denom = 0.f, f0s = 0.f, p1 = 0.f;
    #pragma unroll
    for (int n = 0; n < 16; ++n) {
        bf16x8 w0 = *reinterpret_cast<const bf16x8*>(&sW[(n * 64 + lane) * 8]);
        bf16x8 w1 = *reinterpret_cast<const bf16x8*>(&sW[((16 + n) * 64 + lane) * 8]);
        f32x4 c = *reinterpret_cast<const f32x4*>(&sBias[(n << 4) + (kH << 2)]);
        c = __builtin_amdgcn_mfma_f32_16x16x32_bf16(w0, a0, c, 0, 0, 0);
        c = __builtin_amdgcn_mfma_f32_16x16x32_bf16(w1, a1, c, 0, 0, 0);
        float e0 = __builtin_amdgcn_exp2f(c[0]);
        float e1 = __builtin_amdgcn_exp2f(c[1]);
        float e2 = __builtin_amdgcn_exp2f(c[2]);
        float e3 = __builtin_amdgcn_exp2f(c[3]);
        float bs = (e0 + e1) + (e2 + e3);
        denom += bs;
        float t0 = fmaf(e3, m[3], fmaf(e2, m[2], fmaf(e1, m[1], e0 * m[0])));
        float tp = fmaf(e3, pm[3], fmaf(e2, pm[2], fmaf(e1, pm[1], e0 * pm[0])));
        f0s += (n < sb) ? bs : ((n == sb) ? t0 : 0.f);
        p1  += (n == sb1) ? tp : 0.f;
    }

    // --- reduce over the 4 kH lanes sharing this x-row ---
    denom += __shfl_xor(denom, 16, 64);
    f0s   += __shfl_xor(f0s,   16, 64);
    p1    += __shfl_xor(p1,    16, 64);
    denom += __shfl_xor(denom, 32, 64);
    f0s   += __shfl_xor(f0s,   32, 64);
    p1    += __shfl_xor(p1,    32, 64);

    if (kH == 0) {   // lanes 0..15 store rows m0..m0+15: contiguous 64B -> nt safe
        float x0 = sBP[s], x1 = sBP[s + 1];
        float inv = 1.0f / denom;
        float f0 = f0s * inv;
        float slope = (p1 * inv) / (x1 - x0);
        __builtin_nontemporal_store(fmaf(slope, yv - x0, f0), out + m0 + colb);
        __builtin_nontemporal_store(T.ldv + __logf(fabsf(slope)),
                                    out + (size_t)NB * 65 + m0 + colb);
    }
}

__global__ __launch_bounds__(512, 2) void interp1d_kernel(
    const float* __restrict__ y, const float* __restrict__ x,
    const float* __restrict__ W, const float* __restrict__ bias,
    const float* __restrict__ logdet, const float* __restrict__ bp,
    float* __restrict__ out)
{
    __shared__ unsigned short sW[2 * 16 * 64 * 8];   // 32KB, [kb][n][lane][i] frag layout
    __shared__ unsigned short sX[8 * 16 * 72];       // 18KB: per-wave slab, 144B rows
    __shared__ float sBP[256];
    __shared__ float sBias[256];                     // pre-scaled by log2e

    const int t = threadIdx.x;

    if (t < 256) {
        sBP[t]   = bp[t];
        sBias[t] = bias[t] * LOG2E;
    }
    {
        const int col = t & 255;
        const int k0  = (t >> 8) << 5;
        const int lane16lo = col & 15;
        const int n = col >> 4;
        for (int kk = 0; kk < 32; ++kk) {
            int k = k0 + kk;
            float wv = W[k * 256 + col] * LOG2E;      // coalesced per 256-thread half
            int lane16 = ((k >> 3) & 3) * 16 + lane16lo;
            int kb = k >> 5, i = k & 7;
            sW[((kb * 16 + n) * 64 + lane16) * 8 + i] = f2b(wv);
        }
    }
    __syncthreads();

    const int lane = t & 63;
    const int colb = lane & 15;
    const int kH   = lane >> 4;
    unsigned short* myX = &sX[(t >> 6) * (16 * 72)];
    const int nw = gridDim.x << 3;                    // 8192 waves
    const int wt0 = (blockIdx.x << 3) | (t >> 6);     // 0..8191; tiles wt0 + k*nw, k=0..3

    // --- fully unrolled depth-2 pipeline (NWT == 4*nw exactly; no bounds checks) ---
    Tile T0, T1, T2, T3;
    loadT(T0, wt0,          lane, colb, x, y, logdet);
    loadT(T1, wt0 + nw,     lane, colb, x, y, logdet);

    asm volatile("" ::: "memory");
    loadT(T2, wt0 + 2 * nw, lane, colb, x, y, logdet);   // in flight during T0
    process(T0, wt0,          lane, colb, kH, myX, sW, sBP, sBias, out);

    asm volatile("" ::: "memory");
    loadT(T3, wt0 + 3 * nw, lane, colb, x, y, logdet);   // in flight during T1
    process(T1, wt0 + nw,     lane, colb, kH, myX, sW, sBP, sBias, out);

    asm volatile("" ::: "memory");
    process(T2, wt0 + 2 * nw, lane, colb, kH, myX, sW, sBP, sBias, out);

    asm volatile("" ::: "memory");
    process(T3, wt0 + 3 * nw, lane, colb, kH, myX, sW, sBP, sBias, out);
}

extern "C" void kernel_launch(void* const* d_in, const int* in_sizes, int n_in,
                              void* d_out, int out_size, void* d_ws, size_t ws_size,
                              hipStream_t stream) {
    (void)in_sizes; (void)n_in; (void)out_size; (void)d_ws; (void)ws_size;
    const float* y      = (const float*)d_in[0];
    const float* x      = (const float*)d_in[1];
    const float* W      = (const float*)d_in[2];
    const float* b      = (const float*)d_in[3];
    const float* logdet = (const float*)d_in[4];
    const float* bp     = (const float*)d_in[5];
    float* out = (float*)d_out;
    // 1024 blocks x 512 thr = 8192 waves x 4 tiles = 32768 = NWT exactly.
    // LDS 52KB -> 3 blocks/CU resident; (512,2) budget so no 64-reg squeeze.
    interp1d_kernel<<<dim3(1024), dim3(512), 0, stream>>>(y, x, W, b, logdet, bp, out);
}

// Round 24
// 55.156 us; speedup vs baseline: 3.7744x; 1.0026x over previous
//
#include <hip/hip_runtime.h>
#include <hip/hip_bf16.h>

// Interpolate1D: z = interp(cumsum(softmax(x@W + b)), y); outputs (z[B], x[B,64], logdet[B]+log|slope|)
// B=524288, D=64, R=256.
//
// Round-24 = round-22 body (56.0us; lane-linear mem path) + RESIDENT-EXACT GRID:
//   r22/r23 launched 1024 blocks at 52KB LDS -> only 3 blocks/CU fit -> 768
//   resident + 256 queued. The final ~25% of the kernel runs at 1/3 utilization
//   while stragglers drain (memory-bound tail raggedness). Launch 768 blocks
//   (= 3/CU exactly, all resident start-to-finish), grid-stride 5-6 tiles/wave.
//   r23's depth-2 unroll was neutral (VGPR snapped back to 64; allocator refuses
//   deeper liveness) -> reverted to the simpler r22 loop.
// Kept from r22 (all verified): lane-linear loads + nt full-line stores (WRITE
// 155->136MB confirmed), per-wave LDS transpose slab, fused n-loop, swapped MFMA
// operands, register prefetch, LICM fence, log2e + exp2, float-mask prefix sums,
// branchless searchsorted, nt z/logdet stores.

#define NB 524288
#define NWT (NB / 16)   // 32768 wave-tiles of 16 rows

typedef __attribute__((ext_vector_type(4))) float f32x4;
typedef __attribute__((ext_vector_type(8))) __bf16 bf16x8;

#define LOG2E 1.4426950408889634f

static __device__ __forceinline__ unsigned short f2b(float f) {
    unsigned u = __builtin_bit_cast(unsigned, f);
    u += 0x7fffu + ((u >> 16) & 1u);          // RNE (W pack only; one-time)
    return (unsigned short)(u >> 16);
}
static __device__ __forceinline__ unsigned pk2t(float a, float b) {
    // truncating bf16x2 pack: hi16(a) | hi16(b)
    return (__builtin_bit_cast(unsigned, a) >> 16) | (__builtin_bit_cast(unsigned, b) & 0xffff0000u);
}

__global__ __launch_bounds__(512, 2) void interp1d_kernel(
    const float* __restrict__ y, const float* __restrict__ x,
    const float* __restrict__ W, const float* __restrict__ bias,
    const float* __restrict__ logdet, const float* __restrict__ bp,
    float* __restrict__ out)
{
    __shared__ unsigned short sW[2 * 16 * 64 * 8];   // 32KB, [kb][n][lane][i] frag layout
    __shared__ unsigned short sX[8 * 16 * 72];       // 18KB: per-wave tile slab, 144B/row
    __shared__ float sBP[256];
    __shared__ float sBias[256];                     // pre-scaled by log2e

    const int t = threadIdx.x;

    // --- once per block: bp, bias*log2e, W*log2e packed into MFMA fragment layout ---
    if (t < 256) {
        sBP[t]   = bp[t];
        sBias[t] = bias[t] * LOG2E;
    }
    {
        const int col = t & 255;
        const int k0  = (t >> 8) << 5;
        const int lane16lo = col & 15;
        const int n = col >> 4;
        for (int kk = 0; kk < 32; ++kk) {
            int k = k0 + kk;
            float wv = W[k * 256 + col] * LOG2E;      // coalesced within each 256-thread half
            int lane16 = ((k >> 3) & 3) * 16 + lane16lo;
            int kb = k >> 5, i = k & 7;
            sW[((kb * 16 + n) * 64 + lane16) * 8 + i] = f2b(wv);
        }
    }
    __syncthreads();

    const int lane = t & 63;
    const int colb = lane & 15;     // this lane's x-row within the tile (C column)
    const int kH   = lane >> 4;     // 0..3: k-half for frags; C row group (cols kH*4+j)
    unsigned short* myX = &sX[(t >> 6) * (16 * 72)];   // this wave's private slab
    const int nw   = gridDim.x << 3;                   // 8 waves per block

    int wt = (blockIdx.x << 3) | (t >> 6);

    // --- preload first tile: LANE-LINEAR (1KB contiguous per wave instruction) ---
    f32x4 v0 = {}, v1 = {}, v2 = {}, v3 = {};
    float yv = 0.f, ldv = 0.f;
    if (wt < NWT) {
        const f32x4* xg = reinterpret_cast<const f32x4*>(x) + (size_t)wt * 256;
        v0 = xg[lane]; v1 = xg[64 + lane]; v2 = xg[128 + lane]; v3 = xg[192 + lane];
        yv  = y[(wt << 4) + colb];
        ldv = logdet[(wt << 4) + colb];
    }

    for (; wt < NWT; wt += nw) {
        const int m0 = wt << 4;
        const int wtn = wt + nw;

        // --- prefetch next tile, lane-linear ---
        f32x4 n0 = {}, n1 = {}, n2 = {}, n3 = {};
        float yn = 0.f, ldn = 0.f;
        if (wtn < NWT) {
            const f32x4* xg = reinterpret_cast<const f32x4*>(x) + (size_t)wtn * 256;
            n0 = xg[lane]; n1 = xg[64 + lane]; n2 = xg[128 + lane]; n3 = xg[192 + lane];
            yn  = y[(wtn << 4) + colb];
            ldn = logdet[(wtn << 4) + colb];
        }

        // compiler fence: keep sW ds_reads inside the tile loop (r3 LICM lesson)
        asm volatile("" ::: "memory");

        // --- nt passthrough: same lane-linear registers -> full-line writes ---
        f32x4* xo = reinterpret_cast<f32x4*>(out + NB) + (size_t)wt * 256;
        __builtin_nontemporal_store(v0, xo + lane);
        __builtin_nontemporal_store(v1, xo + 64 + lane);
        __builtin_nontemporal_store(v2, xo + 128 + lane);
        __builtin_nontemporal_store(v3, xo + 192 + lane);

        // --- stage tile to LDS as bf16 (chunk c = j*64+lane -> row c>>4, pos c&15) ---
        {
            uint2 w; int c, row, pos;
            c = lane;        row = c >> 4; pos = c & 15;
            w.x = pk2t(v0[0], v0[1]); w.y = pk2t(v0[2], v0[3]);
            *reinterpret_cast<uint2*>(&myX[row * 72 + pos * 4]) = w;
            c = 64 + lane;   row = c >> 4; pos = c & 15;
            w.x = pk2t(v1[0], v1[1]); w.y = pk2t(v1[2], v1[3]);
            *reinterpret_cast<uint2*>(&myX[row * 72 + pos * 4]) = w;
            c = 128 + lane;  row = c >> 4; pos = c & 15;
            w.x = pk2t(v2[0], v2[1]); w.y = pk2t(v2[2], v2[3]);
            *reinterpret_cast<uint2*>(&myX[row * 72 + pos * 4]) = w;
            c = 192 + lane;  row = c >> 4; pos = c & 15;
            w.x = pk2t(v3[0], v3[1]); w.y = pk2t(v3[2], v3[3]);
            *reinterpret_cast<uint2*>(&myX[row * 72 + pos * 4]) = w;
        }

        // --- read A-frags: 2x ds_read_b128, same-wave (no barrier; compiler lgkmcnt) ---
        bf16x8 a0 = *reinterpret_cast<const bf16x8*>(&myX[colb * 72 + (kH << 3)]);
        bf16x8 a1 = *reinterpret_cast<const bf16x8*>(&myX[colb * 72 + 32 + (kH << 3)]);

        // --- searchsorted (branchless: bp ~ linspace so guess is off by <= 1) ---
        int s = (int)floorf(yv * 255.0f);
        s = min(254, max(0, s));
        s += (sBP[s + 1] <= yv) ? 1 : 0;   // bp[255]=1.0 > yv, can't reach 255
        s = min(s, 254);
        s -= (sBP[s] > yv) ? 1 : 0;
        s = max(s, 0);

        // --- per-lane float masks for the partial blocks ---
        const int sb  = s >> 4,  so  = s & 15;            // block/offset of s
        const int sb1 = (s + 1) >> 4, so1 = (s + 1) & 15; // block/offset of s+1
        float m[4], pm[4];
        #pragma unroll
        for (int j = 0; j < 4; ++j) {
            m[j]  = ((kH << 2) + j <= so)  ? 1.f : 0.f;
            pm[j] = ((kH << 2) + j == so1) ? 1.f : 0.f;
        }

        // --- FUSED n-loop: MFMA (transient c) -> exp2 -> masked sums ---
        float denom = 0.f, f0s = 0.f, p1 = 0.f;
        #pragma unroll
        for (int n = 0; n < 16; ++n) {
            bf16x8 w0 = *reinterpret_cast<const bf16x8*>(&sW[(n * 64 + lane) * 8]);
            bf16x8 w1 = *reinterpret_cast<const bf16x8*>(&sW[((16 + n) * 64 + lane) * 8]);
            f32x4 c = *reinterpret_cast<const f32x4*>(&sBias[(n << 4) + (kH << 2)]);
            c = __builtin_amdgcn_mfma_f32_16x16x32_bf16(w0, a0, c, 0, 0, 0);
            c = __builtin_amdgcn_mfma_f32_16x16x32_bf16(w1, a1, c, 0, 0, 0);
            float e0 = __builtin_amdgcn_exp2f(c[0]);
            float e1 = __builtin_amdgcn_exp2f(c[1]);
            float e2 = __builtin_amdgcn_exp2f(c[2]);
            float e3 = __builtin_amdgcn_exp2f(c[3]);
            float bs = (e0 + e1) + (e2 + e3);
            denom += bs;
            float t0 = fmaf(e3, m[3], fmaf(e2, m[2], fmaf(e1, m[1], e0 * m[0])));
            float tp = fmaf(e3, pm[3], fmaf(e2, pm[2], fmaf(e1, pm[1], e0 * pm[0])));
            f0s += (n < sb) ? bs : ((n == sb) ? t0 : 0.f);
            p1  += (n == sb1) ? tp : 0.f;
        }

        // --- reduce over the 4 kH lanes sharing this x-row ---
        denom += __shfl_xor(denom, 16, 64);
        f0s   += __shfl_xor(f0s,   16, 64);
        p1    += __shfl_xor(p1,    16, 64);
        denom += __shfl_xor(denom, 32, 64);
        f0s   += __shfl_xor(f0s,   32, 64);
        p1    += __shfl_xor(p1,    32, 64);

        if (kH == 0) {   // lanes 0..15 store rows m0..m0+15: contiguous 64B -> nt safe
            float x0 = sBP[s], x1 = sBP[s + 1];
            float inv = 1.0f / denom;
            float f0 = f0s * inv;
            float slope = (p1 * inv) / (x1 - x0);
            __builtin_nontemporal_store(fmaf(slope, yv - x0, f0), out + m0 + colb);
            __builtin_nontemporal_store(ldv + __logf(fabsf(slope)),
                                        out + (size_t)NB * 65 + m0 + colb);
        }

        // --- rotate prefetched tile in ---
        if (wtn < NWT) {
            v0 = n0; v1 = n1; v2 = n2; v3 = n3;
            yv = yn; ldv = ldn;
        }
    }
}

extern "C" void kernel_launch(void* const* d_in, const int* in_sizes, int n_in,
                              void* d_out, int out_size, void* d_ws, size_t ws_size,
                              hipStream_t stream) {
    (void)in_sizes; (void)n_in; (void)out_size; (void)d_ws; (void)ws_size;
    const float* y      = (const float*)d_in[0];
    const float* x      = (const float*)d_in[1];
    const float* W      = (const float*)d_in[2];
    const float* b      = (const float*)d_in[3];
    const float* logdet = (const float*)d_in[4];
    const float* bp     = (const float*)d_in[5];
    float* out = (float*)d_out;
    // 768 blocks = 3 blocks/CU (52KB LDS) EXACTLY resident start-to-finish — no
    // queued-block tail at 1/3 utilization (r22/r23 ran 1024 blocks = 768+256).
    // 6144 waves, 5-6 tiles/wave (bounds-checked grid-stride).
    interp1d_kernel<<<dim3(768), dim3(512), 0, stream>>>(y, x, W, b, logdet, bp, out);
}